// Round 4
// baseline (486.927 us; speedup 1.0000x reference)
//
#include <hip/hip_runtime.h>
#include <math.h>

#define WSP    7
#define HH     112
#define WWID   112
#define BB     4
#define LL     (HH*WWID)     // 12544
#define CC     128
#define NTOK   (HH*WSP)      // 784
#define NKT    13
#define NQT    13
#define NTP    832           // padded tokens (13*64)

typedef __attribute__((ext_vector_type(8))) short bf16x8;
typedef __attribute__((ext_vector_type(4))) float f32x4;

// shorts per ws plane: 256 (b,wi,h)-groups x 832 tokens x 32 ch
#define PLANE_ELEMS (256UL * NTP * 32)
#define WS_NEEDED   (4UL * PLANE_ELEMS * sizeof(short))

__device__ inline short f2bf(float x) {
    unsigned u = __builtin_bit_cast(unsigned, x);
    unsigned r = (u + 0x7fffu + ((u >> 16) & 1u)) >> 16;
    return (short)r;
}
__device__ inline float bf2f(short h) {
    unsigned u = ((unsigned)(unsigned short)h) << 16;
    return __builtin_bit_cast(float, u);
}

// ---- fused LePE + normalize epilogue (shared by both attn variants) ----
__device__ inline void fused_epilogue(float* __restrict__ out,
                                      const float* __restrict__ qkv,
                                      const float* __restrict__ cw,
                                      const float* __restrict__ cbv,
                                      int b, int wi, int chb, int qt, int w, int g, int c,
                                      const f32x4& acc0, const f32x4& acc1, const f32x4& accl) {
    const size_t plane = (size_t)BB * LL * CC;
    const float* vpb = qkv + 2 * plane + (size_t)b * LL * CC;
    #pragma unroll
    for (int r = 0; r < 4; ++r) {
        const int qrow = qt * 64 + w * 16 + g * 4 + r;
        if (qrow >= NTOK) continue;
        const int y = qrow / 7, x = qrow - y * 7;
        const int l = y * WWID + wi * WSP + x;
        const float inv = 1.0f / accl[r];
        float cvs[2];
        #pragma unroll
        for (int cb2 = 0; cb2 < 2; ++cb2) {
            const int ch = chb + cb2 * 16 + c;
            float a = cbv[ch];
            #pragma unroll
            for (int dy = -1; dy <= 1; ++dy) {
                const int yy = y + dy;
                if (yy < 0 || yy >= HH) continue;
                #pragma unroll
                for (int dx = -1; dx <= 1; ++dx) {
                    const int xx = x + dx;
                    if (xx < 0 || xx >= WSP) continue;   // window-local padding
                    a += cw[ch * 9 + (dy + 1) * 3 + (dx + 1)]
                       * vpb[(size_t)(yy * WWID + wi * WSP + xx) * CC + ch];
                }
            }
            cvs[cb2] = a;
        }
        float* o = out + (size_t)b * LL * CC + (size_t)l * CC + chb;
        o[c]      = acc0[r] * inv + cvs[0];
        o[16 + c] = acc1[r] * inv + cvs[1];
    }
}

// ---- prepack: K/V fp32 -> bf16 hi/lo planes in ws (window-contiguous) ----
__global__ __launch_bounds__(256)
void prepack(const float* __restrict__ qkv, short* __restrict__ ws) {
    const int chunk = blockIdx.x;        // 0..12 (64-token chunk)
    const int g2    = blockIdx.y;        // ((b*16+wi)*4 + h)
    const int h  = g2 & 3;
    const int bw = g2 >> 2;
    const int b  = bw >> 4;
    const int wi = bw & 15;
    const int tid = threadIdx.x;
    const int t0 = chunk * 64;

    const size_t plane = (size_t)BB * LL * CC;
    const float* kp = qkv + plane + (size_t)b * LL * CC;
    const float* vp = qkv + 2 * plane + (size_t)b * LL * CC;
    const int chb = h * 32;

    short* Kh = ws;
    short* Kl = ws + PLANE_ELEMS;
    short* Vh = ws + 2 * PLANE_ELEMS;
    short* Vl = ws + 3 * PLANE_ELEMS;

    // K: token-major [g2][t][32]
    {
        const int tk = tid >> 2, dg = tid & 3;
        const int t = t0 + tk;
        const int tc = t < NTOK ? t : NTOK - 1;
        const int l = (tc / 7) * WWID + wi * WSP + (tc % 7);
        const float* p = kp + (size_t)l * CC + chb + dg * 8;
        float4 a0 = *(const float4*)p;
        float4 a1 = *(const float4*)(p + 4);
        float av[8] = {a0.x, a0.y, a0.z, a0.w, a1.x, a1.y, a1.z, a1.w};
        bf16x8 hi8, lo8;
        #pragma unroll
        for (int j = 0; j < 8; ++j) {
            short hi = f2bf(av[j]);
            hi8[j] = hi;
            lo8[j] = f2bf(av[j] - bf2f(hi));
        }
        const size_t o = ((size_t)g2 * NTP + t) * 32 + dg * 8;
        *(bf16x8*)&Kh[o] = hi8;
        *(bf16x8*)&Kl[o] = lo8;
    }
    // V: d-major (transposed) [g2][32][NTP]
    {
        const int d = tid & 31, tg = tid >> 5;
        bf16x8 hi8, lo8;
        #pragma unroll
        for (int j = 0; j < 8; ++j) {
            const int t = t0 + tg * 8 + j;
            const int tc = t < NTOK ? t : NTOK - 1;
            const int l = (tc / 7) * WWID + wi * WSP + (tc % 7);
            const float x = vp[(size_t)l * CC + chb + d];
            short hi = f2bf(x);
            hi8[j] = hi;
            lo8[j] = f2bf(x - bf2f(hi));
        }
        const size_t o = ((size_t)g2 * 32 + d) * NTP + t0 + tg * 8;
        *(bf16x8*)&Vh[o] = hi8;
        *(bf16x8*)&Vl[o] = lo8;
    }
}

// ---- attention, precomputed bf16 K/V, zero barriers ----
__global__ __launch_bounds__(256)
void attn_pre(const float* __restrict__ qkv, const short* __restrict__ ws,
              const float* __restrict__ cw, const float* __restrict__ cbv,
              float* __restrict__ out) {
    const int qt = blockIdx.x;
    const int g2 = blockIdx.y;
    const int h  = g2 & 3;
    const int bw = g2 >> 2;
    const int b  = bw >> 4;
    const int wi = bw & 15;

    const int tid  = threadIdx.x;
    const int w    = tid >> 6;
    const int lane = tid & 63;
    const int g    = lane >> 4;
    const int c    = lane & 15;

    __shared__ __align__(16) short Pl[4][16 * 64];

    const short* Kh = ws + (size_t)g2 * NTP * 32;
    const short* Kl = Kh + PLANE_ELEMS;
    const short* Vh = ws + 2 * PLANE_ELEMS + (size_t)g2 * 32 * NTP;
    const short* Vl = Vh + PLANE_ELEMS;

    const float* qp = qkv + (size_t)b * LL * CC;
    const int chb = h * 32;

    // Q A-frag (hi/lo), scale folded in
    bf16x8 qh, ql;
    {
        int qrow = qt * 64 + w * 16 + c;
        if (qrow >= NTOK) qrow = NTOK - 1;
        const int l = (qrow / 7) * WWID + wi * WSP + (qrow % 7);
        const float* p = qp + (size_t)l * CC + chb + g * 8;
        float4 a0 = *(const float4*)p;
        float4 a1 = *(const float4*)(p + 4);
        float av[8] = {a0.x, a0.y, a0.z, a0.w, a1.x, a1.y, a1.z, a1.w};
        const float scale = 0.17677669529663687f;
        #pragma unroll
        for (int j = 0; j < 8; ++j) {
            float xv = av[j] * scale;
            short hi = f2bf(xv);
            qh[j] = hi;
            ql[j] = f2bf(xv - bf2f(hi));
        }
    }

    const bf16x8 ones = {(short)0x3F80, (short)0x3F80, (short)0x3F80, (short)0x3F80,
                         (short)0x3F80, (short)0x3F80, (short)0x3F80, (short)0x3F80};

    float m_r[4];
    f32x4 acc0 = {0.f, 0.f, 0.f, 0.f};
    f32x4 acc1 = {0.f, 0.f, 0.f, 0.f};
    f32x4 accl = {0.f, 0.f, 0.f, 0.f};
    #pragma unroll
    for (int r = 0; r < 4; ++r) m_r[r] = -INFINITY;

    short* pb = &Pl[w][0];

    for (int kt = 0; kt < NKT; ++kt) {
        // K frags: direct 16B bf16 loads
        bf16x8 kh[4], kl[4];
        #pragma unroll
        for (int f = 0; f < 4; ++f) {
            const size_t o = (size_t)(kt * 64 + f * 16 + c) * 32 + g * 8;
            kh[f] = *(const bf16x8*)&Kh[o];
            kl[f] = *(const bf16x8*)&Kl[o];
        }

        f32x4 sf[4];
        #pragma unroll
        for (int f = 0; f < 4; ++f) {
            f32x4 z = {0.f, 0.f, 0.f, 0.f};
            z = __builtin_amdgcn_mfma_f32_16x16x32_bf16(qh, kh[f], z, 0, 0, 0);
            z = __builtin_amdgcn_mfma_f32_16x16x32_bf16(qh, kl[f], z, 0, 0, 0);
            sf[f] = __builtin_amdgcn_mfma_f32_16x16x32_bf16(ql, kh[f], z, 0, 0, 0);
        }

        #pragma unroll
        for (int f = 0; f < 4; ++f) {
            const int key = kt * 64 + f * 16 + c;
            if (key >= NTOK) {
                sf[f][0] = -INFINITY; sf[f][1] = -INFINITY;
                sf[f][2] = -INFINITY; sf[f][3] = -INFINITY;
            }
        }

        float rmax[4];
        #pragma unroll
        for (int r = 0; r < 4; ++r)
            rmax[r] = fmaxf(fmaxf(sf[0][r], sf[1][r]), fmaxf(sf[2][r], sf[3][r]));
        #pragma unroll
        for (int mk = 1; mk < 16; mk <<= 1)
            #pragma unroll
            for (int r = 0; r < 4; ++r)
                rmax[r] = fmaxf(rmax[r], __shfl_xor(rmax[r], mk, 16));

        float psc[4];
        #pragma unroll
        for (int r = 0; r < 4; ++r) {
            const float mn = fmaxf(m_r[r], rmax[r]);
            psc[r] = __expf(m_r[r] - mn);
            m_r[r] = mn;
        }

        #pragma unroll
        for (int f = 0; f < 4; ++f)
            #pragma unroll
            for (int r = 0; r < 4; ++r)
                sf[f][r] = __expf(sf[f][r] - m_r[r]);

        #pragma unroll
        for (int r = 0; r < 4; ++r) {
            acc0[r] *= psc[r];
            acc1[r] *= psc[r];
            accl[r] *= psc[r];
        }

        // P (bf16) to wave-private LDS, XOR-swizzled
        #pragma unroll
        for (int f = 0; f < 4; ++f)
            #pragma unroll
            for (int r = 0; r < 4; ++r) {
                const int row = g * 4 + r;
                const int off = (f * 16 + c) * 2;
                pb[(row * 128 + (off ^ ((row & 7) << 4))) >> 1] = f2bf(sf[f][r]);
            }

        // PV: A = P (LDS), B = V^T (direct bf16 16B loads)
        #pragma unroll
        for (int s = 0; s < 2; ++s) {
            const int offr = s * 64 + g * 16;
            bf16x8 pa = *(const bf16x8*)&pb[(c * 128 + (offr ^ ((c & 7) << 4))) >> 1];
            const int tbase = kt * 64 + s * 32 + g * 8;
            #pragma unroll
            for (int cb = 0; cb < 2; ++cb) {
                const size_t o = (size_t)(cb * 16 + c) * NTP + tbase;
                bf16x8 vh = *(const bf16x8*)&Vh[o];
                bf16x8 vl = *(const bf16x8*)&Vl[o];
                if (cb == 0) {
                    acc0 = __builtin_amdgcn_mfma_f32_16x16x32_bf16(pa, vh, acc0, 0, 0, 0);
                    acc0 = __builtin_amdgcn_mfma_f32_16x16x32_bf16(pa, vl, acc0, 0, 0, 0);
                } else {
                    acc1 = __builtin_amdgcn_mfma_f32_16x16x32_bf16(pa, vh, acc1, 0, 0, 0);
                    acc1 = __builtin_amdgcn_mfma_f32_16x16x32_bf16(pa, vl, acc1, 0, 0, 0);
                }
            }
            accl = __builtin_amdgcn_mfma_f32_16x16x32_bf16(pa, ones, accl, 0, 0, 0);
        }
    }

    fused_epilogue(out, qkv, cw, cbv, b, wi, chb, qt, w, g, c, acc0, acc1, accl);
}

// ---- fallback (ws too small): round-3 style in-kernel conversion ----
__global__ __launch_bounds__(256)
void attn_fb(const float* __restrict__ qkv, const float* __restrict__ cw,
             const float* __restrict__ cbv, float* __restrict__ out) {
    const int qt = blockIdx.x;
    const int g2 = blockIdx.y;
    const int h  = g2 & 3;
    const int bw = g2 >> 2;
    const int b  = bw >> 4;
    const int wi = bw & 15;

    const int tid  = threadIdx.x;
    const int w    = tid >> 6;
    const int lane = tid & 63;
    const int g    = lane >> 4;
    const int c    = lane & 15;

    __shared__ __align__(16) short Pl[4][16 * 64];
    __shared__ int l_tab[NTP];

    for (int t = tid; t < NTP; t += 256) {
        int tc = t < NTOK ? t : NTOK - 1;
        l_tab[t] = ((tc / 7) * WWID + wi * WSP + (tc % 7)) * CC;
    }
    __syncthreads();

    const size_t plane = (size_t)BB * LL * CC;
    const float* qp = qkv + (size_t)b * LL * CC;
    const float* kp = qp + plane;
    const float* vp = qp + 2 * plane;
    const int chb = h * 32;

    bf16x8 qh, ql;
    {
        const int qrow = qt * 64 + w * 16 + c;
        const float* p = qp + l_tab[qrow < NTP ? qrow : NTP - 1] + chb + g * 8;
        float4 a0 = *(const float4*)p;
        float4 a1 = *(const float4*)(p + 4);
        float av[8] = {a0.x, a0.y, a0.z, a0.w, a1.x, a1.y, a1.z, a1.w};
        const float scale = 0.17677669529663687f;
        #pragma unroll
        for (int j = 0; j < 8; ++j) {
            float xv = av[j] * scale;
            short hi = f2bf(xv);
            qh[j] = hi;
            ql[j] = f2bf(xv - bf2f(hi));
        }
    }

    const bf16x8 ones = {(short)0x3F80, (short)0x3F80, (short)0x3F80, (short)0x3F80,
                         (short)0x3F80, (short)0x3F80, (short)0x3F80, (short)0x3F80};

    float m_r[4];
    f32x4 acc0 = {0.f, 0.f, 0.f, 0.f};
    f32x4 acc1 = {0.f, 0.f, 0.f, 0.f};
    f32x4 accl = {0.f, 0.f, 0.f, 0.f};
    #pragma unroll
    for (int r = 0; r < 4; ++r) m_r[r] = -INFINITY;

    short* pb = &Pl[w][0];

    for (int kt = 0; kt < NKT; ++kt) {
        bf16x8 kh[4], kl[4];
        #pragma unroll
        for (int f = 0; f < 4; ++f) {
            const int t = kt * 64 + f * 16 + c;
            const float* p = kp + l_tab[t] + chb + g * 8;
            float4 a0 = *(const float4*)p;
            float4 a1 = *(const float4*)(p + 4);
            float av[8] = {a0.x, a0.y, a0.z, a0.w, a1.x, a1.y, a1.z, a1.w};
            #pragma unroll
            for (int j = 0; j < 8; ++j) {
                short hi = f2bf(av[j]);
                kh[f][j] = hi;
                kl[f][j] = f2bf(av[j] - bf2f(hi));
            }
        }

        f32x4 sf[4];
        #pragma unroll
        for (int f = 0; f < 4; ++f) {
            f32x4 z = {0.f, 0.f, 0.f, 0.f};
            z = __builtin_amdgcn_mfma_f32_16x16x32_bf16(qh, kh[f], z, 0, 0, 0);
            z = __builtin_amdgcn_mfma_f32_16x16x32_bf16(qh, kl[f], z, 0, 0, 0);
            sf[f] = __builtin_amdgcn_mfma_f32_16x16x32_bf16(ql, kh[f], z, 0, 0, 0);
        }

        #pragma unroll
        for (int f = 0; f < 4; ++f) {
            const int key = kt * 64 + f * 16 + c;
            if (key >= NTOK) {
                sf[f][0] = -INFINITY; sf[f][1] = -INFINITY;
                sf[f][2] = -INFINITY; sf[f][3] = -INFINITY;
            }
        }

        float rmax[4];
        #pragma unroll
        for (int r = 0; r < 4; ++r)
            rmax[r] = fmaxf(fmaxf(sf[0][r], sf[1][r]), fmaxf(sf[2][r], sf[3][r]));
        #pragma unroll
        for (int mk = 1; mk < 16; mk <<= 1)
            #pragma unroll
            for (int r = 0; r < 4; ++r)
                rmax[r] = fmaxf(rmax[r], __shfl_xor(rmax[r], mk, 16));

        float psc[4];
        #pragma unroll
        for (int r = 0; r < 4; ++r) {
            const float mn = fmaxf(m_r[r], rmax[r]);
            psc[r] = __expf(m_r[r] - mn);
            m_r[r] = mn;
        }

        #pragma unroll
        for (int f = 0; f < 4; ++f)
            #pragma unroll
            for (int r = 0; r < 4; ++r)
                sf[f][r] = __expf(sf[f][r] - m_r[r]);

        #pragma unroll
        for (int r = 0; r < 4; ++r) {
            acc0[r] *= psc[r];
            acc1[r] *= psc[r];
            accl[r] *= psc[r];
        }

        #pragma unroll
        for (int f = 0; f < 4; ++f)
            #pragma unroll
            for (int r = 0; r < 4; ++r) {
                const int row = g * 4 + r;
                const int off = (f * 16 + c) * 2;
                pb[(row * 128 + (off ^ ((row & 7) << 4))) >> 1] = f2bf(sf[f][r]);
            }

        #pragma unroll
        for (int s = 0; s < 2; ++s) {
            const int offr = s * 64 + g * 16;
            bf16x8 pa = *(const bf16x8*)&pb[(c * 128 + (offr ^ ((c & 7) << 4))) >> 1];
            const int tbase = kt * 64 + s * 32 + g * 8;
            #pragma unroll
            for (int cb = 0; cb < 2; ++cb) {
                bf16x8 vh, vl;
                #pragma unroll
                for (int j = 0; j < 8; ++j) {
                    const float xv = vp[l_tab[tbase + j] + chb + cb * 16 + c];
                    short hi = f2bf(xv);
                    vh[j] = hi;
                    vl[j] = f2bf(xv - bf2f(hi));
                }
                if (cb == 0) {
                    acc0 = __builtin_amdgcn_mfma_f32_16x16x32_bf16(pa, vh, acc0, 0, 0, 0);
                    acc0 = __builtin_amdgcn_mfma_f32_16x16x32_bf16(pa, vl, acc0, 0, 0, 0);
                } else {
                    acc1 = __builtin_amdgcn_mfma_f32_16x16x32_bf16(pa, vh, acc1, 0, 0, 0);
                    acc1 = __builtin_amdgcn_mfma_f32_16x16x32_bf16(pa, vl, acc1, 0, 0, 0);
                }
            }
            accl = __builtin_amdgcn_mfma_f32_16x16x32_bf16(pa, ones, accl, 0, 0, 0);
        }
    }

    fused_epilogue(out, qkv, cw, cbv, b, wi, chb, qt, w, g, c, acc0, acc1, accl);
}

extern "C" void kernel_launch(void* const* d_in, const int* in_sizes, int n_in,
                              void* d_out, int out_size, void* d_ws, size_t ws_size,
                              hipStream_t stream) {
    const float* qkv = (const float*)d_in[0];
    const float* cw  = (const float*)d_in[1];
    const float* cb  = (const float*)d_in[2];
    float* out = (float*)d_out;

    if (ws_size >= WS_NEEDED) {
        short* ws = (short*)d_ws;
        prepack<<<dim3(NKT, 256), 256, 0, stream>>>(qkv, ws);
        attn_pre<<<dim3(NQT, 256), 256, 0, stream>>>(qkv, ws, cw, cb, out);
    } else {
        attn_fb<<<dim3(NQT, 256), 256, 0, stream>>>(qkv, cw, cb, out);
    }
}